// Round 3
// baseline (565.722 us; speedup 1.0000x reference)
//
#include <hip/hip_runtime.h>
#include <math.h>

#define B 8
#define L 4096
#define C 512          // H*DK == H*DV == 512
#define NF 4096        // FFT length == L
#define TOPK 8
#define CPB 8          // channels per workgroup in corr_fft

typedef short bf16x8 __attribute__((ext_vector_type(8)));
typedef float f32x4 __attribute__((ext_vector_type(4)));

__device__ inline unsigned short f2bf(float f) {
    unsigned int u = __float_as_uint(f);
    u += 0x7FFF + ((u >> 16) & 1);          // round-to-nearest-even
    return (unsigned short)(u >> 16);
}
__device__ inline float bf2f(unsigned short h) {
    return __uint_as_float(((unsigned int)h) << 16);
}

__device__ inline void gload_lds16(const void* g, void* l) {
    __builtin_amdgcn_global_load_lds(
        (const __attribute__((address_space(1))) void*)g,
        (__attribute__((address_space(3))) void*)l, 16, 0, 0);
}

// ---------------------------------------------------------------------------
// f32 -> bf16 elementwise, 8 elems/thread
// ---------------------------------------------------------------------------
__global__ __launch_bounds__(256) void cvt_bf16(const float4* __restrict__ in,
                                                uint4* __restrict__ out) {
    const int gid = blockIdx.x * 256 + threadIdx.x;
    const float4 a = in[gid * 2];
    const float4 b = in[gid * 2 + 1];
    uint4 o;
    o.x = (unsigned)f2bf(a.x) | ((unsigned)f2bf(a.y) << 16);
    o.y = (unsigned)f2bf(a.z) | ((unsigned)f2bf(a.w) << 16);
    o.z = (unsigned)f2bf(b.x) | ((unsigned)f2bf(b.y) << 16);
    o.w = (unsigned)f2bf(b.z) | ((unsigned)f2bf(b.w) << 16);
    out[gid] = o;
}

// ---------------------------------------------------------------------------
// W (512x512 f32, K x N) -> Wt (N x K, bf16), 32x32 LDS tiles
// ---------------------------------------------------------------------------
__global__ __launch_bounds__(256) void wtrans(const float* __restrict__ W,
                                              unsigned short* __restrict__ Wt) {
    __shared__ float t[32][33];
    const int tx = threadIdx.x & 31, ty = threadIdx.x >> 5;   // 32 x 8
    const int bx = blockIdx.x;   // N tile
    const int by = blockIdx.y;   // K tile
#pragma unroll
    for (int i = 0; i < 4; ++i) {
        const int k = by * 32 + ty + i * 8;
        t[ty + i * 8][tx] = W[(size_t)k * 512 + bx * 32 + tx];   // t[k][n]
    }
    __syncthreads();
#pragma unroll
    for (int i = 0; i < 4; ++i) {
        const int n = bx * 32 + ty + i * 8;
        Wt[(size_t)n * 512 + by * 32 + tx] = f2bf(t[tx][ty + i * 8]);
    }
}

// ---------------------------------------------------------------------------
// bf16 MFMA GEMM: A (32768 x 512, row-major bf16) * Bt^T (Bt is N x K bf16)
// -> Out.  TRANSOUT=1: bf16 out at [(b*512+col)*4096 + t]  (b = row>>12)
//          TRANSOUT=0: row-major out, BF16OUT selects ushort vs float.
// 128x128 tile, BK=64, 4 waves (2x2), 4x4 16x16x32 frags per wave.
// ---------------------------------------------------------------------------
template <int TRANSOUT, int BF16OUT>
__global__ __launch_bounds__(256) void gemm_mfma(const unsigned short* __restrict__ A,
                                                 const unsigned short* __restrict__ Bt,
                                                 void* __restrict__ OutP) {
    __shared__ __align__(16) unsigned short Asm[128 * 64];
    __shared__ __align__(16) unsigned short Bsm[128 * 64];
    const int tid = threadIdx.x;
    const int lane = tid & 63;
    const int w = tid >> 6;
    const int wr = w >> 1, wc = w & 1;
    const int row0 = blockIdx.x * 128;
    const int col0 = blockIdx.y * 128;

    const int ldr = tid >> 3;            // 0..31: row within 32-row group
    const int ldk = (tid & 7) << 3;      // k offset (8 bf16 = 16B per lane)
    const int ldsbase = (w << 3) * 64;   // wave's 8-row base within group (ushorts)

    f32x4 acc[4][4] = {};

    for (int k0 = 0; k0 < 512; k0 += 64) {
        __syncthreads();
#pragma unroll
        for (int i = 0; i < 4; ++i) {
            gload_lds16(A  + (size_t)(row0 + i * 32 + ldr) * 512 + k0 + ldk,
                        Asm + i * 32 * 64 + ldsbase);
            gload_lds16(Bt + (size_t)(col0 + i * 32 + ldr) * 512 + k0 + ldk,
                        Bsm + i * 32 * 64 + ldsbase);
        }
        __syncthreads();
#pragma unroll
        for (int kk = 0; kk < 2; ++kk) {
            bf16x8 af[4], bfv[4];
#pragma unroll
            for (int m = 0; m < 4; ++m)
                af[m] = *(const bf16x8*)&Asm[(wr * 64 + m * 16 + (lane & 15)) * 64 +
                                             kk * 32 + (lane >> 4) * 8];
#pragma unroll
            for (int n = 0; n < 4; ++n)
                bfv[n] = *(const bf16x8*)&Bsm[(wc * 64 + n * 16 + (lane & 15)) * 64 +
                                              kk * 32 + (lane >> 4) * 8];
#pragma unroll
            for (int m = 0; m < 4; ++m)
#pragma unroll
                for (int n = 0; n < 4; ++n)
                    acc[m][n] = __builtin_amdgcn_mfma_f32_16x16x32_bf16(
                        af[m], bfv[n], acc[m][n], 0, 0, 0);
        }
    }

    if (TRANSOUT) {
        unsigned short* Out = (unsigned short*)OutP;
        const int bidx = row0 >> 12;
        const int t0base = (row0 & 4095) + wr * 64 + (lane >> 4) * 4;
#pragma unroll
        for (int n = 0; n < 4; ++n) {
            const int col = col0 + wc * 64 + n * 16 + (lane & 15);
#pragma unroll
            for (int m = 0; m < 4; ++m) {
                const int t0 = t0base + m * 16;
                ushort4 v;
                v.x = f2bf(acc[m][n][0]);
                v.y = f2bf(acc[m][n][1]);
                v.z = f2bf(acc[m][n][2]);
                v.w = f2bf(acc[m][n][3]);
                *(ushort4*)&Out[((size_t)(bidx * 512 + col)) * 4096 + t0] = v;
            }
        }
    } else {
#pragma unroll
        for (int m = 0; m < 4; ++m) {
            const int rbase = row0 + wr * 64 + m * 16 + (lane >> 4) * 4;
#pragma unroll
            for (int n = 0; n < 4; ++n) {
                const int col = col0 + wc * 64 + n * 16 + (lane & 15);
#pragma unroll
                for (int j = 0; j < 4; ++j) {
                    if (BF16OUT)
                        ((unsigned short*)OutP)[(size_t)(rbase + j) * 512 + col] =
                            f2bf(acc[m][n][j]);
                    else
                        ((float*)OutP)[(size_t)(rbase + j) * 512 + col] = acc[m][n][j];
                }
            }
        }
    }
}

// ---------------------------------------------------------------------------
// Radix-4 in-place DIF FFT, N=4096, 256 threads, LDS arrays swizzled with
// SWZ(i) = i + (i>>5)  (arrays sized 4224).  Natural-order input; output at
// position p holds X[rev4(p)] (base-4 digit reversal of 6 digits).
// Twiddles via hardware v_sin/v_cos (input in revolutions; angle q/n exact).
// Ends with __syncthreads().
// ---------------------------------------------------------------------------
#define SWZ(i) ((i) + ((i) >> 5))

__device__ __forceinline__ void sincos_rev(float rev, float& s, float& c) {
    const float f = rev - floorf(rev);       // [0,1) revolutions
    s = __builtin_amdgcn_sinf(f);
    c = __builtin_amdgcn_cosf(f);
}

__device__ __forceinline__ int rev4(int p) { // reverse 6 base-4 digits
    unsigned t = __brev((unsigned)p) >> 20;
    return (int)(((t & 0x555u) << 1) | ((t >> 1) & 0x555u));
}

template <int SIGN>   // -1 forward, +1 inverse
__device__ __forceinline__ void fft4096_r4(float* __restrict__ xr,
                                           float* __restrict__ xi,
                                           const int tid) {
#pragma unroll
    for (int stage = 0; stage < 6; ++stage) {
        const int ls = 10 - 2 * stage;
        const int m = 1 << ls;
        const float rn = (float)SIGN / (float)(4 << ls);   // SIGN / n (exact)
#pragma unroll
        for (int gi = 0; gi < 4; ++gi) {
            const int g = tid + gi * 256;
            const int q = g & (m - 1);
            const int base = ((g >> ls) << (ls + 2)) + q;
            const int i0 = SWZ(base);
            const int i1 = SWZ(base + m);
            const int i2 = SWZ(base + 2 * m);
            const int i3 = SWZ(base + 3 * m);
            const float ar = xr[i0], ai = xi[i0];
            const float br = xr[i1], bi = xi[i1];
            const float cr = xr[i2], ci = xi[i2];
            const float dr = xr[i3], di = xi[i3];
            const float t0r = ar + cr, t0i = ai + ci;
            const float t1r = ar - cr, t1i = ai - ci;
            const float t2r = br + dr, t2i = bi + di;
            const float t3r = br - dr, t3i = bi - di;
            const float sgn = (float)SIGN;
            const float X0r = t0r + t2r, X0i = t0i + t2i;
            const float X2r = t0r - t2r, X2i = t0i - t2i;
            const float X1r = t1r - sgn * t3i, X1i = t1i + sgn * t3r;
            const float X3r = t1r + sgn * t3i, X3i = t1i - sgn * t3r;
            const float a1 = rn * (float)q;
            float s1, c1, s2, c2, s3, c3;
            sincos_rev(a1, s1, c1);
            sincos_rev(a1 + a1, s2, c2);
            sincos_rev(a1 + a1 + a1, s3, c3);
            xr[i0] = X0r;                    xi[i0] = X0i;
            xr[i1] = X1r * c1 - X1i * s1;    xi[i1] = X1r * s1 + X1i * c1;
            xr[i2] = X2r * c2 - X2i * s2;    xi[i2] = X2r * s2 + X2i * c2;
            xr[i3] = X3r * c3 - X3i * s3;    xi[i3] = X3r * s3 + X3i * c3;
        }
        __syncthreads();
    }
}

// ---------------------------------------------------------------------------
// Per (b, channel-group): FFT of z = q + i*k (bf16 inputs), cross-spectrum
// Qf*conj(Kf) accumulated over CPB channels, atomicAdd into Pacc[b][f]
// (natural frequency order).
// ---------------------------------------------------------------------------
__global__ __launch_bounds__(256) void corr_fft(const unsigned short* __restrict__ qT,
                                                const unsigned short* __restrict__ kT,
                                                float* __restrict__ Pacc) {
    __shared__ float xr[4224], xi[4224];
    const int wg = blockIdx.x;
    const int b = wg >> 6;               // C/CPB == 64 groups per batch
    const int cg = wg & 63;
    const int tid = threadIdx.x;

    float accR[16] = {}, accI[16] = {};

    for (int cc = 0; cc < CPB; ++cc) {
        const int c = cg * CPB + cc;
        const uint4* q4 = (const uint4*)(qT + ((size_t)(b * C + c)) * L);
        const uint4* k4 = (const uint4*)(kT + ((size_t)(b * C + c)) * L);
        __syncthreads();   // protect LDS from previous iteration's readers
#pragma unroll
        for (int j = 0; j < 2; ++j) {
            const int u = j * 256 + tid;
            const uint4 vq = q4[u];
            const uint4 vk = k4[u];
            const int t0 = u * 8;
            xr[SWZ(t0 + 0)] = bf2f((unsigned short)(vq.x & 0xffff));
            xr[SWZ(t0 + 1)] = bf2f((unsigned short)(vq.x >> 16));
            xr[SWZ(t0 + 2)] = bf2f((unsigned short)(vq.y & 0xffff));
            xr[SWZ(t0 + 3)] = bf2f((unsigned short)(vq.y >> 16));
            xr[SWZ(t0 + 4)] = bf2f((unsigned short)(vq.z & 0xffff));
            xr[SWZ(t0 + 5)] = bf2f((unsigned short)(vq.z >> 16));
            xr[SWZ(t0 + 6)] = bf2f((unsigned short)(vq.w & 0xffff));
            xr[SWZ(t0 + 7)] = bf2f((unsigned short)(vq.w >> 16));
            xi[SWZ(t0 + 0)] = bf2f((unsigned short)(vk.x & 0xffff));
            xi[SWZ(t0 + 1)] = bf2f((unsigned short)(vk.x >> 16));
            xi[SWZ(t0 + 2)] = bf2f((unsigned short)(vk.y & 0xffff));
            xi[SWZ(t0 + 3)] = bf2f((unsigned short)(vk.y >> 16));
            xi[SWZ(t0 + 4)] = bf2f((unsigned short)(vk.z & 0xffff));
            xi[SWZ(t0 + 5)] = bf2f((unsigned short)(vk.z >> 16));
            xi[SWZ(t0 + 6)] = bf2f((unsigned short)(vk.w & 0xffff));
            xi[SWZ(t0 + 7)] = bf2f((unsigned short)(vk.w >> 16));
        }
        __syncthreads();
        fft4096_r4<-1>(xr, xi, tid);     // ends synced; pos p holds Z[rev4(p)]
#pragma unroll
        for (int j = 0; j < 16; ++j) {
            const int p = j * 256 + tid;
            const int k = rev4(p);
            const int kn = (NF - k) & (NF - 1);
            const int pn = rev4(kn);
            const float ar = xr[SWZ(p)],  ai = xi[SWZ(p)];    // Z[k]
            const float br = xr[SWZ(pn)], bi = xi[SWZ(pn)];   // Z[N-k]
            const float qr_ = 0.5f * (ar + br), qi_ = 0.5f * (ai - bi);
            const float kr_ = 0.5f * (ai + bi), ki_ = -0.5f * (ar - br);
            accR[j] += qr_ * kr_ + qi_ * ki_;    // Re(Qf*conj(Kf)) at freq k
            accI[j] += qi_ * kr_ - qr_ * ki_;    // Im
        }
    }
#pragma unroll
    for (int j = 0; j < 16; ++j) {
        const int p = j * 256 + tid;
        const int k = rev4(p);
        atomicAdd(&Pacc[(size_t)b * (2 * NF) + 2 * k + 0], accR[j]);
        atomicAdd(&Pacc[(size_t)b * (2 * NF) + 2 * k + 1], accI[j]);
    }
}

// ---------------------------------------------------------------------------
// Inverse FFT of accumulated cross-spectrum (natural order in) ->
// mean_value[b][tau] (digit-reversed scatter on write).
// ---------------------------------------------------------------------------
__global__ __launch_bounds__(256) void ifft_mean(const float* __restrict__ Pacc,
                                                 float* __restrict__ mean_value) {
    __shared__ float xr[4224], xi[4224];
    const int b = blockIdx.x;
    const int tid = threadIdx.x;
    const float2* pc = (const float2*)(Pacc + (size_t)b * 2 * NF);
#pragma unroll
    for (int j = 0; j < 16; ++j) {
        const int p = j * 256 + tid;
        const float2 v = pc[p];
        xr[SWZ(p)] = v.x;
        xi[SWZ(p)] = v.y;
    }
    __syncthreads();
    fft4096_r4<1>(xr, xi, tid);
    const float scale = 1.0f / ((float)NF * 512.0f);
#pragma unroll
    for (int j = 0; j < 16; ++j) {
        const int p = j * 256 + tid;
        mean_value[(size_t)b * NF + rev4(p)] = xr[SWZ(p)] * scale;
    }
}

// ---------------------------------------------------------------------------
__global__ __launch_bounds__(256) void topk_softmax(const float* __restrict__ mean_value,
                                                    int* __restrict__ idx_out,
                                                    float* __restrict__ tc_out) {
    __shared__ float mv[NF];
    __shared__ float rv[256];
    __shared__ int ri[256];
    __shared__ int sel[TOPK];
    const int tid = threadIdx.x;

    for (int j = 0; j < 16; ++j) {
        const int t = j * 256 + tid;
        float s = 0.f;
        for (int b = 0; b < B; ++b) s += mean_value[(size_t)b * NF + t];
        mv[t] = s * (1.0f / (float)B);
    }
    __syncthreads();

    for (int iter = 0; iter < TOPK; ++iter) {
        float bv = -INFINITY; int bi = NF;
        for (int j = 0; j < 16; ++j) {
            const int t = j * 256 + tid;
            const float v = mv[t];
            if (v > bv || (v == bv && t < bi)) { bv = v; bi = t; }
        }
        rv[tid] = bv; ri[tid] = bi;
        __syncthreads();
        for (int off = 128; off > 0; off >>= 1) {
            if (tid < off) {
                if (rv[tid + off] > rv[tid] ||
                    (rv[tid + off] == rv[tid] && ri[tid + off] < ri[tid])) {
                    rv[tid] = rv[tid + off]; ri[tid] = ri[tid + off];
                }
            }
            __syncthreads();
        }
        if (tid == 0) { sel[iter] = ri[0]; mv[ri[0]] = -INFINITY; }
        __syncthreads();
    }

    if (tid < B) {
        float wv[TOPK];
        float mx = -INFINITY;
        for (int i = 0; i < TOPK; ++i) {
            wv[i] = mean_value[(size_t)tid * NF + sel[i]];
            mx = fmaxf(mx, wv[i]);
        }
        float sum = 0.f;
        for (int i = 0; i < TOPK; ++i) { wv[i] = expf(wv[i] - mx); sum += wv[i]; }
        const float inv = 1.0f / sum;
        for (int i = 0; i < TOPK; ++i) tc_out[tid * TOPK + i] = wv[i] * inv;
    }
    if (tid < TOPK) idx_out[tid] = sel[tid];
}

// ---------------------------------------------------------------------------
// ctx[b][t][c] = sum_i tc[b][i] * vproj[b][(t+idx[i])%L][c]  (bf16 in/out)
// ---------------------------------------------------------------------------
__global__ __launch_bounds__(256) void context_bf16(const unsigned short* __restrict__ vproj,
                                                    const int* __restrict__ idx,
                                                    const float* __restrict__ tc,
                                                    unsigned short* __restrict__ ctx) {
    const size_t gid = (size_t)blockIdx.x * 256 + threadIdx.x;
    const int c8 = (int)(gid & 63);
    const int t  = (int)((gid >> 6) & 4095);
    const int b  = (int)(gid >> 18);

    __shared__ int sIdx[TOPK];
    __shared__ float sW[TOPK];
    if (threadIdx.x < TOPK) {
        sIdx[threadIdx.x] = idx[threadIdx.x];
        sW[threadIdx.x]   = tc[b * TOPK + threadIdx.x];
    }
    __syncthreads();

    const unsigned short* vb = vproj + (size_t)b * L * C;
    float a[8] = {};
#pragma unroll
    for (int i = 0; i < TOPK; ++i) {
        const int row = (t + sIdx[i]) & (L - 1);
        const uint4 v = *(const uint4*)&vb[(size_t)row * C + c8 * 8];
        const float wgt = sW[i];
        a[0] += wgt * bf2f((unsigned short)(v.x & 0xFFFF));
        a[1] += wgt * bf2f((unsigned short)(v.x >> 16));
        a[2] += wgt * bf2f((unsigned short)(v.y & 0xFFFF));
        a[3] += wgt * bf2f((unsigned short)(v.y >> 16));
        a[4] += wgt * bf2f((unsigned short)(v.z & 0xFFFF));
        a[5] += wgt * bf2f((unsigned short)(v.z >> 16));
        a[6] += wgt * bf2f((unsigned short)(v.w & 0xFFFF));
        a[7] += wgt * bf2f((unsigned short)(v.w >> 16));
    }
    uint4 o;
    o.x = (unsigned)f2bf(a[0]) | ((unsigned)f2bf(a[1]) << 16);
    o.y = (unsigned)f2bf(a[2]) | ((unsigned)f2bf(a[3]) << 16);
    o.z = (unsigned)f2bf(a[4]) | ((unsigned)f2bf(a[5]) << 16);
    o.w = (unsigned)f2bf(a[6]) | ((unsigned)f2bf(a[7]) << 16);
    *(uint4*)&ctx[gid * 8] = o;
}

// ---------------------------------------------------------------------------
extern "C" void kernel_launch(void* const* d_in, const int* in_sizes, int n_in,
                              void* d_out, int out_size, void* d_ws, size_t ws_size,
                              hipStream_t stream) {
    const float* Q   = (const float*)d_in[0];
    const float* K   = (const float*)d_in[1];
    const float* V   = (const float*)d_in[2];
    const float* WQ  = (const float*)d_in[4];
    const float* WK  = (const float*)d_in[5];
    const float* WV  = (const float*)d_in[6];
    const float* Wfc = (const float*)d_in[7];
    float* out = (float*)d_out;

    const size_t SZ = (size_t)B * L * C;          // 16,777,216 elements
    unsigned short* Qb   = (unsigned short*)d_ws; // 32 MB
    unsigned short* Kb   = Qb + SZ;               // 32 MB
    unsigned short* qTb  = Kb + SZ;               // 32 MB, (B,C,L) bf16
    unsigned short* kTb  = qTb + SZ;              // 32 MB
    unsigned short* WQt  = kTb + SZ;              // 512 KB each
    unsigned short* WKt  = WQt + 512 * 512;
    unsigned short* WVt  = WKt + 512 * 512;
    unsigned short* Wfct = WVt + 512 * 512;
    float* Pacc       = (float*)(Wfct + 512 * 512);   // B*NF*2
    float* mean_value = Pacc + (size_t)B * NF * 2;    // B*NF
    float* tc         = mean_value + (size_t)B * NF;  // B*TOPK
    int*   idx        = (int*)(tc + B * TOPK);        // TOPK

    // aliases (sequential stream execution makes these safe):
    unsigned short* Vb     = Qb;   // V cast, after GEMM-Q consumed Qb
    unsigned short* vprojb = Kb;   // V projection, after GEMM-K consumed Kb
    unsigned short* ctxb   = qTb;  // context, after corr_fft consumed qTb

    cvt_bf16<<<dim3(8192), 256, 0, stream>>>((const float4*)Q, (uint4*)Qb);
    cvt_bf16<<<dim3(8192), 256, 0, stream>>>((const float4*)K, (uint4*)Kb);
    wtrans<<<dim3(16, 16), 256, 0, stream>>>(WQ, WQt);
    wtrans<<<dim3(16, 16), 256, 0, stream>>>(WK, WKt);
    wtrans<<<dim3(16, 16), 256, 0, stream>>>(WV, WVt);
    wtrans<<<dim3(16, 16), 256, 0, stream>>>(Wfc, Wfct);

    gemm_mfma<1, 1><<<dim3(256, 4), 256, 0, stream>>>(Qb, WQt, qTb);
    gemm_mfma<1, 1><<<dim3(256, 4), 256, 0, stream>>>(Kb, WKt, kTb);

    cvt_bf16<<<dim3(8192), 256, 0, stream>>>((const float4*)V, (uint4*)Vb);
    gemm_mfma<0, 1><<<dim3(256, 4), 256, 0, stream>>>(Vb, WVt, vprojb);

    hipMemsetAsync(Pacc, 0, (size_t)B * NF * 2 * sizeof(float), stream);
    corr_fft<<<dim3(B * (C / CPB)), 256, 0, stream>>>(qTb, kTb, Pacc);
    ifft_mean<<<dim3(B), 256, 0, stream>>>(Pacc, mean_value);
    topk_softmax<<<dim3(1), 256, 0, stream>>>(mean_value, idx, tc);

    context_bf16<<<dim3(8192), 256, 0, stream>>>(vprojb, idx, tc, ctxb);
    gemm_mfma<0, 0><<<dim3(256, 4), 256, 0, stream>>>(ctxb, Wfct, out);
}

// Round 4
// 520.747 us; speedup vs baseline: 1.0864x; 1.0864x over previous
//
#include <hip/hip_runtime.h>
#include <math.h>
#include <utility>

#define B 8
#define L 4096
#define C 512          // H*DK == H*DV == 512
#define NF 4096        // FFT length == L
#define TOPK 8
#define CPW 4          // channels per wave in corr_fft4

typedef short bf16x8 __attribute__((ext_vector_type(8)));
typedef float f32x4 __attribute__((ext_vector_type(4)));

__device__ inline unsigned short f2bf(float f) {
    unsigned int u = __float_as_uint(f);
    u += 0x7FFF + ((u >> 16) & 1);          // round-to-nearest-even
    return (unsigned short)(u >> 16);
}
__device__ inline float bf2f(unsigned short h) {
    return __uint_as_float(((unsigned int)h) << 16);
}

__device__ inline void gload_lds16(const void* g, void* l) {
    __builtin_amdgcn_global_load_lds(
        (const __attribute__((address_space(1))) void*)g,
        (__attribute__((address_space(3))) void*)l, 16, 0, 0);
}

// ---------------------------------------------------------------------------
// f32 -> bf16 elementwise, 8 elems/thread
// ---------------------------------------------------------------------------
__global__ __launch_bounds__(256) void cvt_bf16(const float4* __restrict__ in,
                                                uint4* __restrict__ out) {
    const int gid = blockIdx.x * 256 + threadIdx.x;
    const float4 a = in[gid * 2];
    const float4 b = in[gid * 2 + 1];
    uint4 o;
    o.x = (unsigned)f2bf(a.x) | ((unsigned)f2bf(a.y) << 16);
    o.y = (unsigned)f2bf(a.z) | ((unsigned)f2bf(a.w) << 16);
    o.z = (unsigned)f2bf(b.x) | ((unsigned)f2bf(b.y) << 16);
    o.w = (unsigned)f2bf(b.z) | ((unsigned)f2bf(b.w) << 16);
    out[gid] = o;
}

// ---------------------------------------------------------------------------
// W (512x512 f32, K x N) -> Wt (N x K, bf16), 32x32 LDS tiles
// ---------------------------------------------------------------------------
__global__ __launch_bounds__(256) void wtrans(const float* __restrict__ W,
                                              unsigned short* __restrict__ Wt) {
    __shared__ float t[32][33];
    const int tx = threadIdx.x & 31, ty = threadIdx.x >> 5;   // 32 x 8
    const int bx = blockIdx.x;   // N tile
    const int by = blockIdx.y;   // K tile
#pragma unroll
    for (int i = 0; i < 4; ++i) {
        const int k = by * 32 + ty + i * 8;
        t[ty + i * 8][tx] = W[(size_t)k * 512 + bx * 32 + tx];   // t[k][n]
    }
    __syncthreads();
#pragma unroll
    for (int i = 0; i < 4; ++i) {
        const int n = bx * 32 + ty + i * 8;
        Wt[(size_t)n * 512 + by * 32 + tx] = f2bf(t[tx][ty + i * 8]);
    }
}

// ---------------------------------------------------------------------------
// bf16 MFMA GEMM: A (32768 x 512, row-major bf16) * Bt^T (Bt is N x K bf16)
// -> Out.  TRANSOUT=1: bf16 out at [(b*512+col)*4096 + t]  (b = row>>12)
//          TRANSOUT=0: row-major out, BF16OUT selects ushort vs float.
// 128x128 tile, BK=64, 4 waves (2x2), 4x4 16x16x32 frags per wave.
// ---------------------------------------------------------------------------
template <int TRANSOUT, int BF16OUT>
__global__ __launch_bounds__(256) void gemm_mfma(const unsigned short* __restrict__ A,
                                                 const unsigned short* __restrict__ Bt,
                                                 void* __restrict__ OutP) {
    __shared__ __align__(16) unsigned short Asm[128 * 64];
    __shared__ __align__(16) unsigned short Bsm[128 * 64];
    const int tid = threadIdx.x;
    const int lane = tid & 63;
    const int w = tid >> 6;
    const int wr = w >> 1, wc = w & 1;
    const int row0 = blockIdx.x * 128;
    const int col0 = blockIdx.y * 128;

    const int ldr = tid >> 3;            // 0..31: row within 32-row group
    const int ldk = (tid & 7) << 3;      // k offset (8 bf16 = 16B per lane)
    const int ldsbase = (w << 3) * 64;   // wave's 8-row base within group (ushorts)

    f32x4 acc[4][4] = {};

    for (int k0 = 0; k0 < 512; k0 += 64) {
        __syncthreads();
#pragma unroll
        for (int i = 0; i < 4; ++i) {
            gload_lds16(A  + (size_t)(row0 + i * 32 + ldr) * 512 + k0 + ldk,
                        Asm + i * 32 * 64 + ldsbase);
            gload_lds16(Bt + (size_t)(col0 + i * 32 + ldr) * 512 + k0 + ldk,
                        Bsm + i * 32 * 64 + ldsbase);
        }
        __syncthreads();
#pragma unroll
        for (int kk = 0; kk < 2; ++kk) {
            bf16x8 af[4], bfv[4];
#pragma unroll
            for (int m = 0; m < 4; ++m)
                af[m] = *(const bf16x8*)&Asm[(wr * 64 + m * 16 + (lane & 15)) * 64 +
                                             kk * 32 + (lane >> 4) * 8];
#pragma unroll
            for (int n = 0; n < 4; ++n)
                bfv[n] = *(const bf16x8*)&Bsm[(wc * 64 + n * 16 + (lane & 15)) * 64 +
                                              kk * 32 + (lane >> 4) * 8];
#pragma unroll
            for (int m = 0; m < 4; ++m)
#pragma unroll
                for (int n = 0; n < 4; ++n)
                    acc[m][n] = __builtin_amdgcn_mfma_f32_16x16x32_bf16(
                        af[m], bfv[n], acc[m][n], 0, 0, 0);
        }
    }

    if (TRANSOUT) {
        unsigned short* Out = (unsigned short*)OutP;
        const int bidx = row0 >> 12;
        const int t0base = (row0 & 4095) + wr * 64 + (lane >> 4) * 4;
#pragma unroll
        for (int n = 0; n < 4; ++n) {
            const int col = col0 + wc * 64 + n * 16 + (lane & 15);
#pragma unroll
            for (int m = 0; m < 4; ++m) {
                const int t0 = t0base + m * 16;
                ushort4 v;
                v.x = f2bf(acc[m][n][0]);
                v.y = f2bf(acc[m][n][1]);
                v.z = f2bf(acc[m][n][2]);
                v.w = f2bf(acc[m][n][3]);
                *(ushort4*)&Out[((size_t)(bidx * 512 + col)) * 4096 + t0] = v;
            }
        }
    } else {
#pragma unroll
        for (int m = 0; m < 4; ++m) {
            const int rbase = row0 + wr * 64 + m * 16 + (lane >> 4) * 4;
#pragma unroll
            for (int n = 0; n < 4; ++n) {
                const int col = col0 + wc * 64 + n * 16 + (lane & 15);
#pragma unroll
                for (int j = 0; j < 4; ++j) {
                    if (BF16OUT)
                        ((unsigned short*)OutP)[(size_t)(rbase + j) * 512 + col] =
                            f2bf(acc[m][n][j]);
                    else
                        ((float*)OutP)[(size_t)(rbase + j) * 512 + col] = acc[m][n][j];
                }
            }
        }
    }
}

// ===========================================================================
// In-register 64-point radix-4 DIF FFT machinery (compile-time twiddles)
// ===========================================================================
constexpr double d_sin_t(double x) {
    double t = x, s = x; const double x2 = x * x;
    for (int i = 1; i < 10; ++i) { t *= -x2 / ((2.0 * i) * (2.0 * i + 1.0)); s += t; }
    return s;
}
constexpr double d_cos_t(double x) {
    double t = 1.0, s = 1.0; const double x2 = x * x;
    for (int i = 1; i < 10; ++i) { t *= -x2 / ((2.0 * i - 1.0) * (2.0 * i)); s += t; }
    return s;
}
struct TwTab {
    float c[64]; float s[64];
    constexpr TwTab() : c{}, s{} {
        for (int j = 0; j < 64; ++j) {
            const int q = j >> 4, r = j & 15;
            const double x = 6.283185307179586476925286766559 * r / 64.0;
            const double cc = d_cos_t(x), ss = d_sin_t(x);
            double cv, sv;
            if (q == 0)      { cv =  cc; sv =  ss; }
            else if (q == 1) { cv = -ss; sv =  cc; }
            else if (q == 2) { cv = -cc; sv = -ss; }
            else             { cv =  ss; sv = -cc; }
            c[j] = (float)cv; s[j] = (float)sv;
        }
    }
};
constexpr TwTab TW;

constexpr int rev64c(int p) { return ((p & 3) << 4) | (p & 12) | ((p >> 4) & 3); }

template <int E, int SGN>
__device__ __forceinline__ void twmul(float& xr, float& xi) {
    if constexpr ((E & 63) != 0) {
        constexpr float wc = TW.c[E & 63];
        constexpr float ws = (SGN < 0) ? -TW.s[E & 63] : TW.s[E & 63];
        const float r  = xr * wc - xi * ws;
        const float i2 = xr * ws + xi * wc;
        xr = r; xi = i2;
    }
}

template <int E1, int E2, int E3, int SGN>
__device__ __forceinline__ void bf4(float& ar, float& ai, float& br, float& bi,
                                    float& cr, float& ci, float& er, float& ei) {
    const float t0r = ar + cr, t0i = ai + ci, t1r = ar - cr, t1i = ai - ci;
    const float t2r = br + er, t2i = bi + ei, t3r = br - er, t3i = bi - ei;
    ar = t0r + t2r; ai = t0i + t2i;
    float x2r = t0r - t2r, x2i = t0i - t2i;
    float x1r, x1i, x3r, x3i;
    if (SGN < 0) { x1r = t1r + t3i; x1i = t1i - t3r; x3r = t1r - t3i; x3i = t1i + t3r; }
    else         { x1r = t1r - t3i; x1i = t1i + t3r; x3r = t1r + t3i; x3i = t1i - t3r; }
    twmul<E1, SGN>(x1r, x1i);
    twmul<E2, SGN>(x2r, x2i);
    twmul<E3, SGN>(x3r, x3i);
    br = x1r; bi = x1i;
    cr = x2r; ci = x2i;
    er = x3r; ei = x3i;
}

template <int SGN, int... Is>
__device__ __forceinline__ void fft64_s0(float* dr, float* di, std::integer_sequence<int, Is...>) {
    (bf4<Is, 2 * Is, 3 * Is, SGN>(dr[Is], di[Is], dr[Is + 16], di[Is + 16],
                                  dr[Is + 32], di[Is + 32], dr[Is + 48], di[Is + 48]), ...);
}
template <int SGN, int... Is>
__device__ __forceinline__ void fft64_s1(float* dr, float* di, std::integer_sequence<int, Is...>) {
    (bf4<4 * (Is & 3), 8 * (Is & 3), 12 * (Is & 3), SGN>(
         dr[((Is >> 2) << 4) + (Is & 3)],      di[((Is >> 2) << 4) + (Is & 3)],
         dr[((Is >> 2) << 4) + (Is & 3) + 4],  di[((Is >> 2) << 4) + (Is & 3) + 4],
         dr[((Is >> 2) << 4) + (Is & 3) + 8],  di[((Is >> 2) << 4) + (Is & 3) + 8],
         dr[((Is >> 2) << 4) + (Is & 3) + 12], di[((Is >> 2) << 4) + (Is & 3) + 12]), ...);
}
template <int SGN, int... Is>
__device__ __forceinline__ void fft64_s2(float* dr, float* di, std::integer_sequence<int, Is...>) {
    (bf4<0, 0, 0, SGN>(dr[4 * Is], di[4 * Is], dr[4 * Is + 1], di[4 * Is + 1],
                       dr[4 * Is + 2], di[4 * Is + 2], dr[4 * Is + 3], di[4 * Is + 3]), ...);
}
template <int SGN>
__device__ __forceinline__ void fft64(float* dr, float* di) {
    fft64_s0<SGN>(dr, di, std::make_integer_sequence<int, 16>{});
    fft64_s1<SGN>(dr, di, std::make_integer_sequence<int, 16>{});
    fft64_s2<SGN>(dr, di, std::make_integer_sequence<int, 16>{});
}

// mid twiddle: reg p holds Y[lane][k2=rev64(p)]; multiply by W4096^(lane*k2)
template <int P>
__device__ __forceinline__ void mid1(float* dr, float* di, int lane) {
    constexpr int K2 = rev64c(P);
    if constexpr (K2 != 0) {
        const float a = (float)(lane * K2) * (1.0f / 4096.0f);
        const float f = a - floorf(a);
        const float s = __builtin_amdgcn_sinf(f);
        const float c = __builtin_amdgcn_cosf(f);
        const float xr = dr[P], xi = di[P];
        dr[P] = xr * c + xi * s;      // multiply by (c, -s)
        di[P] = xi * c - xr * s;
    }
}
template <int... Ps>
__device__ __forceinline__ void midtwiddle(float* dr, float* di, int lane,
                                           std::integer_sequence<int, Ps...>) {
    (mid1<Ps>(dr, di, lane), ...);
}

// transpose helpers: tile is [64][64] f32, rotate-swizzled addr = row*64 + ((col+row)&63)
template <int... Ps>
__device__ __forceinline__ void twrite(float* tile, const float* d, int lane,
                                       std::integer_sequence<int, Ps...>) {
    ((tile[(lane << 6) + ((rev64c(Ps) + lane) & 63)] = d[Ps]), ...);
}
template <int... Rs>
__device__ __forceinline__ void tread(float* tile, float* d, int lane,
                                      std::integer_sequence<int, Rs...>) {
    ((d[Rs] = tile[(Rs << 6) + ((lane + Rs) & 63)]), ...);
}

__device__ __forceinline__ void lds_fence() {
    asm volatile("s_waitcnt lgkmcnt(0)" ::: "memory");
    __builtin_amdgcn_sched_barrier(0);
}

// square + LDS accumulate: after FFT2, lane=k2, reg p -> k1=rev64(p); k = k2 + 64*k1
template <int P>
__device__ __forceinline__ void sqacc1(const float* dr, const float* di, int lane,
                                       float* accR, float* accI) {
    constexpr int K1 = rev64c(P);
    const int k = lane + (K1 << 6);
    const float ur = dr[P] * dr[P] - di[P] * di[P];
    const float ui = 2.0f * dr[P] * di[P];
    atomicAdd(&accR[k], ur);
    atomicAdd(&accI[k], ui);
}
template <int... Ps>
__device__ __forceinline__ void sqacc(const float* dr, const float* di, int lane,
                                      float* accR, float* accI,
                                      std::integer_sequence<int, Ps...>) {
    (sqacc1<Ps>(dr, di, lane, accR, accI), ...);
}

// ---------------------------------------------------------------------------
// corr_fft4: one wave per 4096-pt FFT (four-step 64x64), CPW channels/wave.
// z = q + i*krev; accumulate Z^2 into per-block LDS; flush via global atomics.
// Im(ifft(sum Z^2))/2 = sum_c corr_c.
// grid = 256 blocks (32 per batch), 256 threads.
// ---------------------------------------------------------------------------
__global__ __launch_bounds__(256) void corr_fft4(const unsigned short* __restrict__ qT,
                                                 const unsigned short* __restrict__ kT,
                                                 float* __restrict__ Pacc) {
    __shared__ float tile[4][4096];
    __shared__ float accR[4096];
    __shared__ float accI[4096];
    const int tid = threadIdx.x, lane = tid & 63, wv = tid >> 6;
    const int b = blockIdx.x >> 5;          // 32 blocks per batch
    const int local = blockIdx.x & 31;

    for (int i = tid; i < 4096; i += 256) { accR[i] = 0.f; accI[i] = 0.f; }
    __syncthreads();

    float dr[64], di[64];
    float* tl = tile[wv];
    constexpr auto seq64 = std::make_integer_sequence<int, 64>{};

#pragma unroll 1
    for (int cc = 0; cc < CPW; ++cc) {
        const int c = local * (4 * CPW) + wv * CPW + cc;
        const unsigned short* qrow = qT + ((size_t)(b * C + c)) * L;
        const unsigned short* krow = kT + ((size_t)(b * C + c)) * L;
#pragma unroll
        for (int n2 = 0; n2 < 64; ++n2) {
            dr[n2] = bf2f(qrow[lane + (n2 << 6)]);
            di[n2] = bf2f(krow[(4096 - lane - (n2 << 6)) & 4095]);
        }
        fft64<-1>(dr, di);                 // Y[lane][k2=rev(p)]
        midtwiddle(dr, di, lane, seq64);   // * W4096^(lane*k2)
        twrite(tl, dr, lane, seq64); lds_fence();
        tread(tl, dr, lane, seq64); lds_fence();
        twrite(tl, di, lane, seq64); lds_fence();
        tread(tl, di, lane, seq64); lds_fence();
        fft64<-1>(dr, di);                 // X[k2=lane + 64*rev(p)]
        sqacc(dr, di, lane, accR, accI, seq64);
    }

    __syncthreads();
    float* dst = Pacc + (size_t)b * (2 * NF);
    for (int i = tid; i < 4096; i += 256) {
        atomicAdd(&dst[2 * i],     accR[i]);
        atomicAdd(&dst[2 * i + 1], accI[i]);
    }
}

// ---------------------------------------------------------------------------
// Radix-4 in-place DIF FFT in LDS (kept for ifft_mean), N=4096, 256 threads.
// ---------------------------------------------------------------------------
#define SWZ(i) ((i) + ((i) >> 5))

__device__ __forceinline__ void sincos_rev(float rev, float& s, float& c) {
    const float f = rev - floorf(rev);
    s = __builtin_amdgcn_sinf(f);
    c = __builtin_amdgcn_cosf(f);
}

__device__ __forceinline__ int rev4(int p) { // reverse 6 base-4 digits
    unsigned t = __brev((unsigned)p) >> 20;
    return (int)(((t & 0x555u) << 1) | ((t >> 1) & 0x555u));
}

template <int SIGN>
__device__ __forceinline__ void fft4096_r4(float* __restrict__ xr,
                                           float* __restrict__ xi,
                                           const int tid) {
#pragma unroll
    for (int stage = 0; stage < 6; ++stage) {
        const int ls = 10 - 2 * stage;
        const int m = 1 << ls;
        const float rn = (float)SIGN / (float)(4 << ls);
#pragma unroll
        for (int gi = 0; gi < 4; ++gi) {
            const int g = tid + gi * 256;
            const int q = g & (m - 1);
            const int base = ((g >> ls) << (ls + 2)) + q;
            const int i0 = SWZ(base);
            const int i1 = SWZ(base + m);
            const int i2 = SWZ(base + 2 * m);
            const int i3 = SWZ(base + 3 * m);
            const float ar = xr[i0], ai = xi[i0];
            const float br = xr[i1], bi = xi[i1];
            const float cr = xr[i2], ci = xi[i2];
            const float dr = xr[i3], di = xi[i3];
            const float t0r = ar + cr, t0i = ai + ci;
            const float t1r = ar - cr, t1i = ai - ci;
            const float t2r = br + dr, t2i = bi + di;
            const float t3r = br - dr, t3i = bi - di;
            const float sgn = (float)SIGN;
            const float X0r = t0r + t2r, X0i = t0i + t2i;
            const float X2r = t0r - t2r, X2i = t0i - t2i;
            const float X1r = t1r - sgn * t3i, X1i = t1i + sgn * t3r;
            const float X3r = t1r + sgn * t3i, X3i = t1i - sgn * t3r;
            const float a1 = rn * (float)q;
            float s1, c1, s2, c2, s3, c3;
            sincos_rev(a1, s1, c1);
            sincos_rev(a1 + a1, s2, c2);
            sincos_rev(a1 + a1 + a1, s3, c3);
            xr[i0] = X0r;                    xi[i0] = X0i;
            xr[i1] = X1r * c1 - X1i * s1;    xi[i1] = X1r * s1 + X1i * c1;
            xr[i2] = X2r * c2 - X2i * s2;    xi[i2] = X2r * s2 + X2i * c2;
            xr[i3] = X3r * c3 - X3i * s3;    xi[i3] = X3r * s3 + X3i * c3;
        }
        __syncthreads();
    }
}

// ---------------------------------------------------------------------------
// Inverse FFT of accumulated S = sum Z^2 (natural order) -> mean_value:
// mean_value[tau] = Im(N*ifft(S))[tau] / (2*N*512)
// ---------------------------------------------------------------------------
__global__ __launch_bounds__(256) void ifft_mean(const float* __restrict__ Pacc,
                                                 float* __restrict__ mean_value) {
    __shared__ float xr[4224], xi[4224];
    const int b = blockIdx.x;
    const int tid = threadIdx.x;
    const float2* pc = (const float2*)(Pacc + (size_t)b * 2 * NF);
#pragma unroll
    for (int j = 0; j < 16; ++j) {
        const int p = j * 256 + tid;
        const float2 v = pc[p];
        xr[SWZ(p)] = v.x;
        xi[SWZ(p)] = v.y;
    }
    __syncthreads();
    fft4096_r4<1>(xr, xi, tid);
    const float scale = 1.0f / (2.0f * 4096.0f * 512.0f);
#pragma unroll
    for (int j = 0; j < 16; ++j) {
        const int p = j * 256 + tid;
        mean_value[(size_t)b * NF + rev4(p)] = xi[SWZ(p)] * scale;
    }
}

// ---------------------------------------------------------------------------
__global__ __launch_bounds__(256) void topk_softmax(const float* __restrict__ mean_value,
                                                    int* __restrict__ idx_out,
                                                    float* __restrict__ tc_out) {
    __shared__ float mv[NF];
    __shared__ float rv[256];
    __shared__ int ri[256];
    __shared__ int sel[TOPK];
    const int tid = threadIdx.x;

    for (int j = 0; j < 16; ++j) {
        const int t = j * 256 + tid;
        float s = 0.f;
        for (int b = 0; b < B; ++b) s += mean_value[(size_t)b * NF + t];
        mv[t] = s * (1.0f / (float)B);
    }
    __syncthreads();

    for (int iter = 0; iter < TOPK; ++iter) {
        float bv = -INFINITY; int bi = NF;
        for (int j = 0; j < 16; ++j) {
            const int t = j * 256 + tid;
            const float v = mv[t];
            if (v > bv || (v == bv && t < bi)) { bv = v; bi = t; }
        }
        rv[tid] = bv; ri[tid] = bi;
        __syncthreads();
        for (int off = 128; off > 0; off >>= 1) {
            if (tid < off) {
                if (rv[tid + off] > rv[tid] ||
                    (rv[tid + off] == rv[tid] && ri[tid + off] < ri[tid])) {
                    rv[tid] = rv[tid + off]; ri[tid] = ri[tid + off];
                }
            }
            __syncthreads();
        }
        if (tid == 0) { sel[iter] = ri[0]; mv[ri[0]] = -INFINITY; }
        __syncthreads();
    }

    if (tid < B) {
        float wv[TOPK];
        float mx = -INFINITY;
        for (int i = 0; i < TOPK; ++i) {
            wv[i] = mean_value[(size_t)tid * NF + sel[i]];
            mx = fmaxf(mx, wv[i]);
        }
        float sum = 0.f;
        for (int i = 0; i < TOPK; ++i) { wv[i] = expf(wv[i] - mx); sum += wv[i]; }
        const float inv = 1.0f / sum;
        for (int i = 0; i < TOPK; ++i) tc_out[tid * TOPK + i] = wv[i] * inv;
    }
    if (tid < TOPK) idx_out[tid] = sel[tid];
}

// ---------------------------------------------------------------------------
// ctx[b][t][c] = sum_i tc[b][i] * vproj[b][(t+idx[i])%L][c]  (bf16 in/out)
// ---------------------------------------------------------------------------
__global__ __launch_bounds__(256) void context_bf16(const unsigned short* __restrict__ vproj,
                                                    const int* __restrict__ idx,
                                                    const float* __restrict__ tc,
                                                    unsigned short* __restrict__ ctx) {
    const size_t gid = (size_t)blockIdx.x * 256 + threadIdx.x;
    const int c8 = (int)(gid & 63);
    const int t  = (int)((gid >> 6) & 4095);
    const int b  = (int)(gid >> 18);

    __shared__ int sIdx[TOPK];
    __shared__ float sW[TOPK];
    if (threadIdx.x < TOPK) {
        sIdx[threadIdx.x] = idx[threadIdx.x];
        sW[threadIdx.x]   = tc[b * TOPK + threadIdx.x];
    }
    __syncthreads();

    const unsigned short* vb = vproj + (size_t)b * L * C;
    float a[8] = {};
#pragma unroll
    for (int i = 0; i < TOPK; ++i) {
        const int row = (t + sIdx[i]) & (L - 1);
        const uint4 v = *(const uint4*)&vb[(size_t)row * C + c8 * 8];
        const float wgt = sW[i];
        a[0] += wgt * bf2f((unsigned short)(v.x & 0xFFFF));
        a[1] += wgt * bf2f((unsigned short)(v.x >> 16));
        a[2] += wgt * bf2f((unsigned short)(v.y & 0xFFFF));
        a[3] += wgt * bf2f((unsigned short)(v.y >> 16));
        a[4] += wgt * bf2f((unsigned short)(v.z & 0xFFFF));
        a[5] += wgt * bf2f((unsigned short)(v.z >> 16));
        a[6] += wgt * bf2f((unsigned short)(v.w & 0xFFFF));
        a[7] += wgt * bf2f((unsigned short)(v.w >> 16));
    }
    uint4 o;
    o.x = (unsigned)f2bf(a[0]) | ((unsigned)f2bf(a[1]) << 16);
    o.y = (unsigned)f2bf(a[2]) | ((unsigned)f2bf(a[3]) << 16);
    o.z = (unsigned)f2bf(a[4]) | ((unsigned)f2bf(a[5]) << 16);
    o.w = (unsigned)f2bf(a[6]) | ((unsigned)f2bf(a[7]) << 16);
    *(uint4*)&ctx[gid * 8] = o;
}

// ---------------------------------------------------------------------------
extern "C" void kernel_launch(void* const* d_in, const int* in_sizes, int n_in,
                              void* d_out, int out_size, void* d_ws, size_t ws_size,
                              hipStream_t stream) {
    const float* Q   = (const float*)d_in[0];
    const float* K   = (const float*)d_in[1];
    const float* V   = (const float*)d_in[2];
    const float* WQ  = (const float*)d_in[4];
    const float* WK  = (const float*)d_in[5];
    const float* WV  = (const float*)d_in[6];
    const float* Wfc = (const float*)d_in[7];
    float* out = (float*)d_out;

    const size_t SZ = (size_t)B * L * C;          // 16,777,216 elements
    unsigned short* Qb   = (unsigned short*)d_ws; // 32 MB
    unsigned short* Kb   = Qb + SZ;               // 32 MB
    unsigned short* qTb  = Kb + SZ;               // 32 MB, (B,C,L) bf16
    unsigned short* kTb  = qTb + SZ;              // 32 MB
    unsigned short* WQt  = kTb + SZ;              // 512 KB each
    unsigned short* WKt  = WQt + 512 * 512;
    unsigned short* WVt  = WKt + 512 * 512;
    unsigned short* Wfct = WVt + 512 * 512;
    float* Pacc       = (float*)(Wfct + 512 * 512);   // B*NF*2
    float* mean_value = Pacc + (size_t)B * NF * 2;    // B*NF
    float* tc         = mean_value + (size_t)B * NF;  // B*TOPK
    int*   idx        = (int*)(tc + B * TOPK);        // TOPK

    // aliases (sequential stream execution makes these safe):
    unsigned short* Vb     = Qb;   // V cast, after GEMM-Q consumed Qb
    unsigned short* vprojb = Kb;   // V projection, after GEMM-K consumed Kb
    unsigned short* ctxb   = qTb;  // context, after corr_fft consumed qTb

    cvt_bf16<<<dim3(8192), 256, 0, stream>>>((const float4*)Q, (uint4*)Qb);
    cvt_bf16<<<dim3(8192), 256, 0, stream>>>((const float4*)K, (uint4*)Kb);
    wtrans<<<dim3(16, 16), 256, 0, stream>>>(WQ, WQt);
    wtrans<<<dim3(16, 16), 256, 0, stream>>>(WK, WKt);
    wtrans<<<dim3(16, 16), 256, 0, stream>>>(WV, WVt);
    wtrans<<<dim3(16, 16), 256, 0, stream>>>(Wfc, Wfct);

    gemm_mfma<1, 1><<<dim3(256, 4), 256, 0, stream>>>(Qb, WQt, qTb);
    gemm_mfma<1, 1><<<dim3(256, 4), 256, 0, stream>>>(Kb, WKt, kTb);

    cvt_bf16<<<dim3(8192), 256, 0, stream>>>((const float4*)V, (uint4*)Vb);
    gemm_mfma<0, 1><<<dim3(256, 4), 256, 0, stream>>>(Vb, WVt, vprojb);

    hipMemsetAsync(Pacc, 0, (size_t)B * NF * 2 * sizeof(float), stream);
    corr_fft4<<<dim3(256), 256, 0, stream>>>(qTb, kTb, Pacc);
    ifft_mean<<<dim3(B), 256, 0, stream>>>(Pacc, mean_value);
    topk_softmax<<<dim3(1), 256, 0, stream>>>(mean_value, idx, tc);

    context_bf16<<<dim3(8192), 256, 0, stream>>>(vprojb, idx, tc, ctxb);
    gemm_mfma<0, 0><<<dim3(256, 4), 256, 0, stream>>>(ctxb, Wfct, out);
}

// Round 5
// 478.560 us; speedup vs baseline: 1.1821x; 1.0882x over previous
//
#include <hip/hip_runtime.h>
#include <math.h>
#include <utility>

#define B 8
#define L 4096
#define C 512          // H*DK == H*DV == 512
#define NF 4096        // FFT length == L
#define TOPK 8
#define CPW 4          // channels per wave in corr_fft4

typedef short bf16x8 __attribute__((ext_vector_type(8)));
typedef float f32x4 __attribute__((ext_vector_type(4)));

__device__ inline unsigned short f2bf(float f) {
    unsigned int u = __float_as_uint(f);
    u += 0x7FFF + ((u >> 16) & 1);          // round-to-nearest-even
    return (unsigned short)(u >> 16);
}
__device__ inline float bf2f(unsigned short h) {
    return __uint_as_float(((unsigned int)h) << 16);
}

__device__ inline void gload_lds16(const void* g, void* l) {
    __builtin_amdgcn_global_load_lds(
        (const __attribute__((address_space(1))) void*)g,
        (__attribute__((address_space(3))) void*)l, 16, 0, 0);
}

// ---------------------------------------------------------------------------
// f32 -> bf16 elementwise, 8 elems/thread
// ---------------------------------------------------------------------------
__global__ __launch_bounds__(256) void cvt_bf16(const float4* __restrict__ in,
                                                uint4* __restrict__ out) {
    const int gid = blockIdx.x * 256 + threadIdx.x;
    const float4 a = in[gid * 2];
    const float4 b = in[gid * 2 + 1];
    uint4 o;
    o.x = (unsigned)f2bf(a.x) | ((unsigned)f2bf(a.y) << 16);
    o.y = (unsigned)f2bf(a.z) | ((unsigned)f2bf(a.w) << 16);
    o.z = (unsigned)f2bf(b.x) | ((unsigned)f2bf(b.y) << 16);
    o.w = (unsigned)f2bf(b.z) | ((unsigned)f2bf(b.w) << 16);
    out[gid] = o;
}

// ---------------------------------------------------------------------------
// W (512x512 f32, K x N) -> Wt (N x K, bf16), 32x32 LDS tiles
// ---------------------------------------------------------------------------
__global__ __launch_bounds__(256) void wtrans(const float* __restrict__ W,
                                              unsigned short* __restrict__ Wt) {
    __shared__ float t[32][33];
    const int tx = threadIdx.x & 31, ty = threadIdx.x >> 5;   // 32 x 8
    const int bx = blockIdx.x;   // N tile
    const int by = blockIdx.y;   // K tile
#pragma unroll
    for (int i = 0; i < 4; ++i) {
        const int k = by * 32 + ty + i * 8;
        t[ty + i * 8][tx] = W[(size_t)k * 512 + bx * 32 + tx];   // t[k][n]
    }
    __syncthreads();
#pragma unroll
    for (int i = 0; i < 4; ++i) {
        const int n = bx * 32 + ty + i * 8;
        Wt[(size_t)n * 512 + by * 32 + tx] = f2bf(t[tx][ty + i * 8]);
    }
}

// ---------------------------------------------------------------------------
// bf16 MFMA GEMM: A (32768 x 512, row-major bf16) * Bt^T (Bt is N x K bf16)
// -> Out.  TRANSOUT=1: bf16 out at [(b*512+col)*4096 + t]  (b = row>>12)
//          TRANSOUT=0: row-major out, BF16OUT selects ushort vs float.
// 128x128 tile, BK=64, 4 waves (2x2), 4x4 16x16x32 frags per wave.
// ---------------------------------------------------------------------------
template <int TRANSOUT, int BF16OUT>
__global__ __launch_bounds__(256) void gemm_mfma(const unsigned short* __restrict__ A,
                                                 const unsigned short* __restrict__ Bt,
                                                 void* __restrict__ OutP) {
    __shared__ __align__(16) unsigned short Asm[128 * 64];
    __shared__ __align__(16) unsigned short Bsm[128 * 64];
    const int tid = threadIdx.x;
    const int lane = tid & 63;
    const int w = tid >> 6;
    const int wr = w >> 1, wc = w & 1;
    const int row0 = blockIdx.x * 128;
    const int col0 = blockIdx.y * 128;

    const int ldr = tid >> 3;            // 0..31: row within 32-row group
    const int ldk = (tid & 7) << 3;      // k offset (8 bf16 = 16B per lane)
    const int ldsbase = (w << 3) * 64;   // wave's 8-row base within group (ushorts)

    f32x4 acc[4][4] = {};

    for (int k0 = 0; k0 < 512; k0 += 64) {
        __syncthreads();
#pragma unroll
        for (int i = 0; i < 4; ++i) {
            gload_lds16(A  + (size_t)(row0 + i * 32 + ldr) * 512 + k0 + ldk,
                        Asm + i * 32 * 64 + ldsbase);
            gload_lds16(Bt + (size_t)(col0 + i * 32 + ldr) * 512 + k0 + ldk,
                        Bsm + i * 32 * 64 + ldsbase);
        }
        __syncthreads();
#pragma unroll
        for (int kk = 0; kk < 2; ++kk) {
            bf16x8 af[4], bfv[4];
#pragma unroll
            for (int m = 0; m < 4; ++m)
                af[m] = *(const bf16x8*)&Asm[(wr * 64 + m * 16 + (lane & 15)) * 64 +
                                             kk * 32 + (lane >> 4) * 8];
#pragma unroll
            for (int n = 0; n < 4; ++n)
                bfv[n] = *(const bf16x8*)&Bsm[(wc * 64 + n * 16 + (lane & 15)) * 64 +
                                              kk * 32 + (lane >> 4) * 8];
#pragma unroll
            for (int m = 0; m < 4; ++m)
#pragma unroll
                for (int n = 0; n < 4; ++n)
                    acc[m][n] = __builtin_amdgcn_mfma_f32_16x16x32_bf16(
                        af[m], bfv[n], acc[m][n], 0, 0, 0);
        }
    }

    if (TRANSOUT) {
        unsigned short* Out = (unsigned short*)OutP;
        const int bidx = row0 >> 12;
        const int t0base = (row0 & 4095) + wr * 64 + (lane >> 4) * 4;
#pragma unroll
        for (int n = 0; n < 4; ++n) {
            const int col = col0 + wc * 64 + n * 16 + (lane & 15);
#pragma unroll
            for (int m = 0; m < 4; ++m) {
                const int t0 = t0base + m * 16;
                ushort4 v;
                v.x = f2bf(acc[m][n][0]);
                v.y = f2bf(acc[m][n][1]);
                v.z = f2bf(acc[m][n][2]);
                v.w = f2bf(acc[m][n][3]);
                *(ushort4*)&Out[((size_t)(bidx * 512 + col)) * 4096 + t0] = v;
            }
        }
    } else {
#pragma unroll
        for (int m = 0; m < 4; ++m) {
            const int rbase = row0 + wr * 64 + m * 16 + (lane >> 4) * 4;
#pragma unroll
            for (int n = 0; n < 4; ++n) {
                const int col = col0 + wc * 64 + n * 16 + (lane & 15);
#pragma unroll
                for (int j = 0; j < 4; ++j) {
                    if (BF16OUT)
                        ((unsigned short*)OutP)[(size_t)(rbase + j) * 512 + col] =
                            f2bf(acc[m][n][j]);
                    else
                        ((float*)OutP)[(size_t)(rbase + j) * 512 + col] = acc[m][n][j];
                }
            }
        }
    }
}

// ===========================================================================
// In-register 64-point radix-4 DIF FFT machinery (compile-time twiddles)
// ===========================================================================
constexpr double d_sin_t(double x) {
    double t = x, s = x; const double x2 = x * x;
    for (int i = 1; i < 10; ++i) { t *= -x2 / ((2.0 * i) * (2.0 * i + 1.0)); s += t; }
    return s;
}
constexpr double d_cos_t(double x) {
    double t = 1.0, s = 1.0; const double x2 = x * x;
    for (int i = 1; i < 10; ++i) { t *= -x2 / ((2.0 * i - 1.0) * (2.0 * i)); s += t; }
    return s;
}
struct TwTab {
    float c[64]; float s[64];
    constexpr TwTab() : c{}, s{} {
        for (int j = 0; j < 64; ++j) {
            const int q = j >> 4, r = j & 15;
            const double x = 6.283185307179586476925286766559 * r / 64.0;
            const double cc = d_cos_t(x), ss = d_sin_t(x);
            double cv, sv;
            if (q == 0)      { cv =  cc; sv =  ss; }
            else if (q == 1) { cv = -ss; sv =  cc; }
            else if (q == 2) { cv = -cc; sv = -ss; }
            else             { cv =  ss; sv = -cc; }
            c[j] = (float)cv; s[j] = (float)sv;
        }
    }
};
constexpr TwTab TW;

__device__ __host__ constexpr int rev64c(int p) {
    return ((p & 3) << 4) | (p & 12) | ((p >> 4) & 3);
}

template <int E, int SGN>
__device__ __forceinline__ void twmul(float& xr, float& xi) {
    if constexpr ((E & 63) != 0) {
        constexpr float wc = TW.c[E & 63];
        constexpr float ws = (SGN < 0) ? -TW.s[E & 63] : TW.s[E & 63];
        const float r  = xr * wc - xi * ws;
        const float i2 = xr * ws + xi * wc;
        xr = r; xi = i2;
    }
}

template <int E1, int E2, int E3, int SGN>
__device__ __forceinline__ void bf4(float& ar, float& ai, float& br, float& bi,
                                    float& cr, float& ci, float& er, float& ei) {
    const float t0r = ar + cr, t0i = ai + ci, t1r = ar - cr, t1i = ai - ci;
    const float t2r = br + er, t2i = bi + ei, t3r = br - er, t3i = bi - ei;
    ar = t0r + t2r; ai = t0i + t2i;
    float x2r = t0r - t2r, x2i = t0i - t2i;
    float x1r, x1i, x3r, x3i;
    if (SGN < 0) { x1r = t1r + t3i; x1i = t1i - t3r; x3r = t1r - t3i; x3i = t1i + t3r; }
    else         { x1r = t1r - t3i; x1i = t1i + t3r; x3r = t1r + t3i; x3i = t1i - t3r; }
    twmul<E1, SGN>(x1r, x1i);
    twmul<E2, SGN>(x2r, x2i);
    twmul<E3, SGN>(x3r, x3i);
    br = x1r; bi = x1i;
    cr = x2r; ci = x2i;
    er = x3r; ei = x3i;
}

template <int SGN, int... Is>
__device__ __forceinline__ void fft64_s0(float* dr, float* di, std::integer_sequence<int, Is...>) {
    (bf4<Is, 2 * Is, 3 * Is, SGN>(dr[Is], di[Is], dr[Is + 16], di[Is + 16],
                                  dr[Is + 32], di[Is + 32], dr[Is + 48], di[Is + 48]), ...);
}
template <int SGN, int... Is>
__device__ __forceinline__ void fft64_s1(float* dr, float* di, std::integer_sequence<int, Is...>) {
    (bf4<4 * (Is & 3), 8 * (Is & 3), 12 * (Is & 3), SGN>(
         dr[((Is >> 2) << 4) + (Is & 3)],      di[((Is >> 2) << 4) + (Is & 3)],
         dr[((Is >> 2) << 4) + (Is & 3) + 4],  di[((Is >> 2) << 4) + (Is & 3) + 4],
         dr[((Is >> 2) << 4) + (Is & 3) + 8],  di[((Is >> 2) << 4) + (Is & 3) + 8],
         dr[((Is >> 2) << 4) + (Is & 3) + 12], di[((Is >> 2) << 4) + (Is & 3) + 12]), ...);
}
template <int SGN, int... Is>
__device__ __forceinline__ void fft64_s2(float* dr, float* di, std::integer_sequence<int, Is...>) {
    (bf4<0, 0, 0, SGN>(dr[4 * Is], di[4 * Is], dr[4 * Is + 1], di[4 * Is + 1],
                       dr[4 * Is + 2], di[4 * Is + 2], dr[4 * Is + 3], di[4 * Is + 3]), ...);
}
template <int SGN>
__device__ __forceinline__ void fft64(float* dr, float* di) {
    fft64_s0<SGN>(dr, di, std::make_integer_sequence<int, 16>{});
    fft64_s1<SGN>(dr, di, std::make_integer_sequence<int, 16>{});
    fft64_s2<SGN>(dr, di, std::make_integer_sequence<int, 16>{});
}

// mid twiddle: reg p holds Y[lane][k2=rev64(p)]; multiply by W4096^(lane*k2)
template <int P>
__device__ __forceinline__ void mid1(float* dr, float* di, int lane) {
    constexpr int K2 = rev64c(P);
    if constexpr (K2 != 0) {
        const float a = (float)(lane * K2) * (1.0f / 4096.0f);
        const float f = a - floorf(a);
        const float s = __builtin_amdgcn_sinf(f);
        const float c = __builtin_amdgcn_cosf(f);
        const float xr = dr[P], xi = di[P];
        dr[P] = xr * c + xi * s;      // multiply by (c, -s)
        di[P] = xi * c - xr * s;
    }
}
template <int... Ps>
__device__ __forceinline__ void midtwiddle(float* dr, float* di, int lane,
                                           std::integer_sequence<int, Ps...>) {
    (mid1<Ps>(dr, di, lane), ...);
}

// transpose helpers: tile is [64][64] f32, rotate-swizzled addr = row*64 + ((col+row)&63)
template <int... Ps>
__device__ __forceinline__ void twrite(float* tile, const float* d, int lane,
                                       std::integer_sequence<int, Ps...>) {
    ((tile[(lane << 6) + ((rev64c(Ps) + lane) & 63)] = d[Ps]), ...);
}
template <int... Rs>
__device__ __forceinline__ void tread(float* tile, float* d, int lane,
                                      std::integer_sequence<int, Rs...>) {
    ((d[Rs] = tile[(Rs << 6) + ((lane + Rs) & 63)]), ...);
}

__device__ __forceinline__ void lds_fence() {
    asm volatile("s_waitcnt lgkmcnt(0)" ::: "memory");
    __builtin_amdgcn_sched_barrier(0);
}

// ---------------------------------------------------------------------------
// corr_fft4: ONE WAVE per block (64 thr), __launch_bounds__(64,1) -> 512 VGPR
// cap, no spills. Four-step 64x64 FFT fully in registers; Z^2 accumulated in
// registers across CPW channels; single global-atomic flush per wave.
// z = q + i*krev; Im(ifft(sum Z^2))/2 = sum_c corr_c.
// grid = B*C/CPW = 1024 blocks.
// ---------------------------------------------------------------------------
__global__ __launch_bounds__(64, 1) void corr_fft4(const unsigned short* __restrict__ qT,
                                                   const unsigned short* __restrict__ kT,
                                                   float* __restrict__ Pacc) {
    __shared__ float tr_[4096];   // 16 KB re transpose tile
    __shared__ float ti_[4096];   // 16 KB im transpose tile
    const int lane = threadIdx.x;
    const int wg = blockIdx.x;           // 0..1023
    const int b = wg >> 7;               // 128 waves per batch
    const int local = wg & 127;

    float dr[64], di[64], aR[64], aI[64];
#pragma unroll
    for (int p = 0; p < 64; ++p) { aR[p] = 0.f; aI[p] = 0.f; }

    constexpr auto seq64 = std::make_integer_sequence<int, 64>{};

#pragma unroll 1
    for (int cc = 0; cc < CPW; ++cc) {
        const int c = local * CPW + cc;
        const unsigned short* qrow = qT + ((size_t)(b * C + c)) * L;
        const unsigned short* krow = kT + ((size_t)(b * C + c)) * L;
#pragma unroll
        for (int n2 = 0; n2 < 64; ++n2) {
            dr[n2] = bf2f(qrow[lane + (n2 << 6)]);
            di[n2] = bf2f(krow[(4096 - lane - (n2 << 6)) & 4095]);
        }
        fft64<-1>(dr, di);                 // Y[lane][k2=rev(p)]
        midtwiddle(dr, di, lane, seq64);   // * W4096^(lane*k2)
        twrite(tr_, dr, lane, seq64);
        twrite(ti_, di, lane, seq64);
        lds_fence();
        tread(tr_, dr, lane, seq64);
        tread(ti_, di, lane, seq64);
        lds_fence();
        fft64<-1>(dr, di);                 // X[k = lane + 64*rev(p)]
#pragma unroll
        for (int p = 0; p < 64; ++p) {     // accumulate Z^2 in registers
            aR[p] += dr[p] * dr[p] - di[p] * di[p];
            aI[p] += 2.0f * dr[p] * di[p];
        }
    }

    float* dst = Pacc + (size_t)b * (2 * NF);
#pragma unroll
    for (int p = 0; p < 64; ++p) {
        const int k = lane + (rev64c(p) << 6);
        atomicAdd(&dst[2 * k],     aR[p]);
        atomicAdd(&dst[2 * k + 1], aI[p]);
    }
}

// ---------------------------------------------------------------------------
// Radix-4 in-place DIF FFT in LDS (kept for ifft_mean), N=4096, 256 threads.
// ---------------------------------------------------------------------------
#define SWZ(i) ((i) + ((i) >> 5))

__device__ __forceinline__ void sincos_rev(float rev, float& s, float& c) {
    const float f = rev - floorf(rev);
    s = __builtin_amdgcn_sinf(f);
    c = __builtin_amdgcn_cosf(f);
}

__device__ __forceinline__ int rev4(int p) { // reverse 6 base-4 digits
    unsigned t = __brev((unsigned)p) >> 20;
    return (int)(((t & 0x555u) << 1) | ((t >> 1) & 0x555u));
}

template <int SIGN>
__device__ __forceinline__ void fft4096_r4(float* __restrict__ xr,
                                           float* __restrict__ xi,
                                           const int tid) {
#pragma unroll
    for (int stage = 0; stage < 6; ++stage) {
        const int ls = 10 - 2 * stage;
        const int m = 1 << ls;
        const float rn = (float)SIGN / (float)(4 << ls);
#pragma unroll
        for (int gi = 0; gi < 4; ++gi) {
            const int g = tid + gi * 256;
            const int q = g & (m - 1);
            const int base = ((g >> ls) << (ls + 2)) + q;
            const int i0 = SWZ(base);
            const int i1 = SWZ(base + m);
            const int i2 = SWZ(base + 2 * m);
            const int i3 = SWZ(base + 3 * m);
            const float ar = xr[i0], ai = xi[i0];
            const float br = xr[i1], bi = xi[i1];
            const float cr = xr[i2], ci = xi[i2];
            const float dr = xr[i3], di = xi[i3];
            const float t0r = ar + cr, t0i = ai + ci;
            const float t1r = ar - cr, t1i = ai - ci;
            const float t2r = br + dr, t2i = bi + di;
            const float t3r = br - dr, t3i = bi - di;
            const float sgn = (float)SIGN;
            const float X0r = t0r + t2r, X0i = t0i + t2i;
            const float X2r = t0r - t2r, X2i = t0i - t2i;
            const float X1r = t1r - sgn * t3i, X1i = t1i + sgn * t3r;
            const float X3r = t1r + sgn * t3i, X3i = t1i - sgn * t3r;
            const float a1 = rn * (float)q;
            float s1, c1, s2, c2, s3, c3;
            sincos_rev(a1, s1, c1);
            sincos_rev(a1 + a1, s2, c2);
            sincos_rev(a1 + a1 + a1, s3, c3);
            xr[i0] = X0r;                    xi[i0] = X0i;
            xr[i1] = X1r * c1 - X1i * s1;    xi[i1] = X1r * s1 + X1i * c1;
            xr[i2] = X2r * c2 - X2i * s2;    xi[i2] = X2r * s2 + X2i * c2;
            xr[i3] = X3r * c3 - X3i * s3;    xi[i3] = X3r * s3 + X3i * c3;
        }
        __syncthreads();
    }
}

// ---------------------------------------------------------------------------
// Inverse FFT of accumulated S = sum Z^2 (natural order) -> mean_value:
// mean_value[tau] = Im(N*ifft(S))[tau] / (2*N*512)
// ---------------------------------------------------------------------------
__global__ __launch_bounds__(256) void ifft_mean(const float* __restrict__ Pacc,
                                                 float* __restrict__ mean_value) {
    __shared__ float xr[4224], xi[4224];
    const int b = blockIdx.x;
    const int tid = threadIdx.x;
    const float2* pc = (const float2*)(Pacc + (size_t)b * 2 * NF);
#pragma unroll
    for (int j = 0; j < 16; ++j) {
        const int p = j * 256 + tid;
        const float2 v = pc[p];
        xr[SWZ(p)] = v.x;
        xi[SWZ(p)] = v.y;
    }
    __syncthreads();
    fft4096_r4<1>(xr, xi, tid);
    const float scale = 1.0f / (2.0f * 4096.0f * 512.0f);
#pragma unroll
    for (int j = 0; j < 16; ++j) {
        const int p = j * 256 + tid;
        mean_value[(size_t)b * NF + rev4(p)] = xi[SWZ(p)] * scale;
    }
}

// ---------------------------------------------------------------------------
__global__ __launch_bounds__(256) void topk_softmax(const float* __restrict__ mean_value,
                                                    int* __restrict__ idx_out,
                                                    float* __restrict__ tc_out) {
    __shared__ float mv[NF];
    __shared__ float rv[256];
    __shared__ int ri[256];
    __shared__ int sel[TOPK];
    const int tid = threadIdx.x;

    for (int j = 0; j < 16; ++j) {
        const int t = j * 256 + tid;
        float s = 0.f;
        for (int b = 0; b < B; ++b) s += mean_value[(size_t)b * NF + t];
        mv[t] = s * (1.0f / (float)B);
    }
    __syncthreads();

    for (int iter = 0; iter < TOPK; ++iter) {
        float bv = -INFINITY; int bi = NF;
        for (int j = 0; j < 16; ++j) {
            const int t = j * 256 + tid;
            const float v = mv[t];
            if (v > bv || (v == bv && t < bi)) { bv = v; bi = t; }
        }
        rv[tid] = bv; ri[tid] = bi;
        __syncthreads();
        for (int off = 128; off > 0; off >>= 1) {
            if (tid < off) {
                if (rv[tid + off] > rv[tid] ||
                    (rv[tid + off] == rv[tid] && ri[tid + off] < ri[tid])) {
                    rv[tid] = rv[tid + off]; ri[tid] = ri[tid + off];
                }
            }
            __syncthreads();
        }
        if (tid == 0) { sel[iter] = ri[0]; mv[ri[0]] = -INFINITY; }
        __syncthreads();
    }

    if (tid < B) {
        float wv[TOPK];
        float mx = -INFINITY;
        for (int i = 0; i < TOPK; ++i) {
            wv[i] = mean_value[(size_t)tid * NF + sel[i]];
            mx = fmaxf(mx, wv[i]);
        }
        float sum = 0.f;
        for (int i = 0; i < TOPK; ++i) { wv[i] = expf(wv[i] - mx); sum += wv[i]; }
        const float inv = 1.0f / sum;
        for (int i = 0; i < TOPK; ++i) tc_out[tid * TOPK + i] = wv[i] * inv;
    }
    if (tid < TOPK) idx_out[tid] = sel[tid];
}

// ---------------------------------------------------------------------------
// ctx[b][t][c] = sum_i tc[b][i] * vproj[b][(t+idx[i])%L][c]  (bf16 in/out)
// ---------------------------------------------------------------------------
__global__ __launch_bounds__(256) void context_bf16(const unsigned short* __restrict__ vproj,
                                                    const int* __restrict__ idx,
                                                    const float* __restrict__ tc,
                                                    unsigned short* __restrict__ ctx) {
    const size_t gid = (size_t)blockIdx.x * 256 + threadIdx.x;
    const int c8 = (int)(gid & 63);
    const int t  = (int)((gid >> 6) & 4095);
    const int b  = (int)(gid >> 18);

    __shared__ int sIdx[TOPK];
    __shared__ float sW[TOPK];
    if (threadIdx.x < TOPK) {
        sIdx[threadIdx.x] = idx[threadIdx.x];
        sW[threadIdx.x]   = tc[b * TOPK + threadIdx.x];
    }
    __syncthreads();

    const unsigned short* vb = vproj + (size_t)b * L * C;
    float a[8] = {};
#pragma unroll
    for (int i = 0; i < TOPK; ++i) {
        const int row = (t + sIdx[i]) & (L - 1);
        const uint4 v = *(const uint4*)&vb[(size_t)row * C + c8 * 8];
        const float wgt = sW[i];
        a[0] += wgt * bf2f((unsigned short)(v.x & 0xFFFF));
        a[1] += wgt * bf2f((unsigned short)(v.x >> 16));
        a[2] += wgt * bf2f((unsigned short)(v.y & 0xFFFF));
        a[3] += wgt * bf2f((unsigned short)(v.y >> 16));
        a[4] += wgt * bf2f((unsigned short)(v.z & 0xFFFF));
        a[5] += wgt * bf2f((unsigned short)(v.z >> 16));
        a[6] += wgt * bf2f((unsigned short)(v.w & 0xFFFF));
        a[7] += wgt * bf2f((unsigned short)(v.w >> 16));
    }
    uint4 o;
    o.x = (unsigned)f2bf(a[0]) | ((unsigned)f2bf(a[1]) << 16);
    o.y = (unsigned)f2bf(a[2]) | ((unsigned)f2bf(a[3]) << 16);
    o.z = (unsigned)f2bf(a[4]) | ((unsigned)f2bf(a[5]) << 16);
    o.w = (unsigned)f2bf(a[6]) | ((unsigned)f2bf(a[7]) << 16);
    *(uint4*)&ctx[gid * 8] = o;
}

// ---------------------------------------------------------------------------
extern "C" void kernel_launch(void* const* d_in, const int* in_sizes, int n_in,
                              void* d_out, int out_size, void* d_ws, size_t ws_size,
                              hipStream_t stream) {
    const float* Q   = (const float*)d_in[0];
    const float* K   = (const float*)d_in[1];
    const float* V   = (const float*)d_in[2];
    const float* WQ  = (const float*)d_in[4];
    const float* WK  = (const float*)d_in[5];
    const float* WV  = (const float*)d_in[6];
    const float* Wfc = (const float*)d_in[7];
    float* out = (float*)d_out;

    const size_t SZ = (size_t)B * L * C;          // 16,777,216 elements
    unsigned short* Qb   = (unsigned short*)d_ws; // 32 MB
    unsigned short* Kb   = Qb + SZ;               // 32 MB
    unsigned short* qTb  = Kb + SZ;               // 32 MB, (B,C,L) bf16
    unsigned short* kTb  = qTb + SZ;              // 32 MB
    unsigned short* WQt  = kTb + SZ;              // 512 KB each
    unsigned short* WKt  = WQt + 512 * 512;
    unsigned short* WVt  = WKt + 512 * 512;
    unsigned short* Wfct = WVt + 512 * 512;
    float* Pacc       = (float*)(Wfct + 512 * 512);   // B*NF*2
    float* mean_value = Pacc + (size_t)B * NF * 2;    // B*NF
    float* tc         = mean_value + (size_t)B * NF;  // B*TOPK
    int*   idx        = (int*)(tc + B * TOPK);        // TOPK

    // aliases (sequential stream execution makes these safe):
    unsigned short* Vb     = Qb;   // V cast, after GEMM-Q consumed Qb
    unsigned short* vprojb = Kb;   // V projection, after GEMM-K consumed Kb
    unsigned short* ctxb   = qTb;  // context, after corr_fft consumed qTb

    cvt_bf16<<<dim3(8192), 256, 0, stream>>>((const float4*)Q, (uint4*)Qb);
    cvt_bf16<<<dim3(8192), 256, 0, stream>>>((const float4*)K, (uint4*)Kb);
    wtrans<<<dim3(16, 16), 256, 0, stream>>>(WQ, WQt);
    wtrans<<<dim3(16, 16), 256, 0, stream>>>(WK, WKt);
    wtrans<<<dim3(16, 16), 256, 0, stream>>>(WV, WVt);
    wtrans<<<dim3(16, 16), 256, 0, stream>>>(Wfc, Wfct);

    gemm_mfma<1, 1><<<dim3(256, 4), 256, 0, stream>>>(Qb, WQt, qTb);
    gemm_mfma<1, 1><<<dim3(256, 4), 256, 0, stream>>>(Kb, WKt, kTb);

    cvt_bf16<<<dim3(8192), 256, 0, stream>>>((const float4*)V, (uint4*)Vb);
    gemm_mfma<0, 1><<<dim3(256, 4), 256, 0, stream>>>(Vb, WVt, vprojb);

    hipMemsetAsync(Pacc, 0, (size_t)B * NF * 2 * sizeof(float), stream);
    corr_fft4<<<dim3(B * C / CPW), 64, 0, stream>>>(qTb, kTb, Pacc);
    ifft_mean<<<dim3(B), 256, 0, stream>>>(Pacc, mean_value);
    topk_softmax<<<dim3(1), 256, 0, stream>>>(mean_value, idx, tc);

    context_bf16<<<dim3(8192), 256, 0, stream>>>(vprojb, idx, tc, ctxb);
    gemm_mfma<0, 0><<<dim3(256, 4), 256, 0, stream>>>(ctxb, Wfct, out);
}